// Round 22
// baseline (267.022 us; speedup 1.0000x reference)
//
#include <hip/hip_runtime.h>
#include <math.h>

#define BB 512
#define NN 1000
#define DD 128
#define HH 8
#define TILE 125   // 8 tiles of 125 rows; 4000 float4/tile

// ws layout: flag@0 (4B) | Afold@4096: [B][128][8] f32 (2 MB)
#define WS_AFOLD 4096

__device__ __forceinline__ bool mask_feasible(const void* mask, int flag, int idx) {
    if (flag == 1) return ((const int*)mask)[idx] != 0;
    if (flag == 2) return ((const float*)mask)[idx] != 0.0f;
    return ((const unsigned char*)mask)[idx] != 0;
}

// async 16B global->LDS DMA: per-lane global src addr; LDS dest is
// wave-uniform base + lane*16 (HW). No VGPR round-trip, can't spill.
__device__ __forceinline__ void gload_lds16(const float4* g, float4* l) {
    __builtin_amdgcn_global_load_lds(
        (const __attribute__((address_space(1))) void*)g,
        (__attribute__((address_space(3))) void*)l,
        16, 0, 0);
}

// Fused: mask-dtype detect (block 0) + mean over N -> q -> Afold[c][h].
// (validated R4/R12/R19; single-arg launch_bounds only — R5: 2nd arg caused spill.)
__global__ __launch_bounds__(512) void kA_meanfold(
    const float* __restrict__ emb, const float* __restrict__ ctx,
    const float* __restrict__ W_fixed, const float* __restrict__ W_step,
    const float* __restrict__ W_node, float* __restrict__ Afold,
    const unsigned int* __restrict__ maskw, int* __restrict__ flag) {
    int b = blockIdx.x, t = threadIdx.x;
    // ---- k0 fused: detect action_mask storage dtype (block 0, wave 0) ----
    if (b == 0 && t < 64) {
        unsigned int w = maskw[t];
        unsigned long long bi = __ballot(w <= 1u);
        unsigned long long bf = __ballot(w == 0u || w == 0x3F800000u);
        if (t == 0) {
            int f = 0;
            if (bi == ~0ull) f = 1;
            else if (bf == ~0ull) f = 2;
            *flag = f;
        }
    }
    __shared__ float4 red[512];
    __shared__ float mean_s[DD], cld[2 * DD], qlds[DD];
    int q4 = t & 31, j = t >> 5;
    const float4* e4 = (const float4*)(emb + (size_t)b * NN * DD);
    float4 acc = {0.f, 0.f, 0.f, 0.f};
    for (int n = j; n < NN; n += 16) {
        float4 v = e4[n * 32 + q4];
        acc.x += v.x; acc.y += v.y; acc.z += v.z; acc.w += v.w;
    }
    red[t] = acc;
    __syncthreads();
    for (int s = 8; s >= 1; s >>= 1) {
        if (j < s) {
            float4 o = red[t + s * 32], m = red[t];
            m.x += o.x; m.y += o.y; m.z += o.z; m.w += o.w;
            red[t] = m;
        }
        __syncthreads();
    }
    if (t < 32) {
        float4 m = red[t];
        const float inv = 1.0f / (float)NN;
        ((float4*)mean_s)[t] = make_float4(m.x * inv, m.y * inv, m.z * inv, m.w * inv);
    }
    if (t >= 256) cld[t - 256] = ctx[b * 2 * DD + (t - 256)];
    __syncthreads();
    if (t < 128) {
        float a = 0.f;
        for (int c = 0; c < DD; ++c)     a += mean_s[c] * W_fixed[c * DD + t];
        for (int c = 0; c < 2 * DD; ++c) a += cld[c] * W_step[c * DD + t];
        qlds[t] = a;
    }
    __syncthreads();
    if (t < 128) {
        const float* wrow = W_node + (size_t)t * 3 * DD;   // Wk cols [0,128)
        float* A2 = Afold + (size_t)b * 1024;
        for (int h = 0; h < HH; ++h) {
            float a = 0.f;
#pragma unroll
            for (int d0 = 0; d0 < 16; ++d0) a += wrow[h * 16 + d0] * qlds[h * 16 + d0];
            A2[t * 8 + h] = 0.25f * a;   // 1/sqrt(dk) folded
        }
    }
}

// R19's kB with ONE tail delta: coalesced half-wave-per-row logits
// (R9-validated pattern: 32 lanes read 512 contiguous B, 5-shfl reduce).
// Flash loop / SGPR-A compat / DMA staging byte-identical to R19.
__global__ __launch_bounds__(256) void kB_flash(
    const float* __restrict__ emb, const float* __restrict__ Afold,
    const void* __restrict__ mask, const int* __restrict__ flagp,
    const float* __restrict__ W_node, const float* __restrict__ W_out,
    float* __restrict__ out) {
    int b = blockIdx.x, t = threadIdx.x;
    int flag = *flagp;
    int wave = t >> 6, lane = t & 63;
    int hq = (t >> 7) * 4;               // waves 0,1 -> h0..3 ; 2,3 -> h4..7
    int n = t & 127;                     // compat row (valid < TILE)
    int c4 = t & 31, jr = t >> 5;        // accumulate role (jr 0..7)

    __shared__ float4 tile4[128][32];    // 64 KB staged tile (XOR-swizzled); reused as j-reduce scratch
    __shared__ float cbuf[128][8];       // 4 KB: p values
    __shared__ float wemb_s[8][128];
    __shared__ float small[3 * DD];      // hl / gl / g2
    __shared__ float zl[HH];

    // wave-uniform scalar base into A: Afold[b][.][hq..hq+3]
    int hqs = __builtin_amdgcn_readfirstlane(hq);
    const float* AbW = Afold + (size_t)b * 1024 + hqs;

    float4 wacc[8];
#pragma unroll
    for (int h = 0; h < HH; ++h) wacc[h] = make_float4(0.f, 0.f, 0.f, 0.f);
    float zrun = 0.f;                    // meaningful on t<8 only

    const float4* embB4 = (const float4*)(emb + (size_t)b * NN * DD);
    const int mbase = b * NN;
    float4* tl = (float4*)tile4;

    for (int tile = 0; tile < 8; ++tile) {
        int n0 = tile * TILE;
        // ---- stage tile -> LDS via async DMA (wave-uniform LDS base,
        //      per-lane pre-swizzled global source; layout == R12) ----
        for (int i = wave; i < 63; i += 4) {
            int p0 = i * 64;                     // wave-uniform linear base
            int p = p0 + lane;
            int r = p >> 5; if (r > 124) r = 124;   // clamp tail overread
            int c = (p & 31) ^ (r & 31);
            gload_lds16(embB4 + (size_t)(n0 + r) * 32 + c, &tl[p0]);
        }
        __syncthreads();                         // drains vmcnt before reads
        // ---- compat from LDS -> p = exp(compat); A from SGPRs ----
        if (n < TILE) {
            int sw = n & 31;
            float4 s = make_float4(0.f, 0.f, 0.f, 0.f);
#pragma unroll 8
            for (int k = 0; k < 32; ++k) {          // col quad c = 4k..4k+3
                float4 e = tile4[n][k ^ sw];
                const float* ak = AbW + k * 32;     // A[4k+j][hq+i] = ak[j*8+i]
                s.x += e.x * ak[0] + e.y * ak[8]  + e.z * ak[16] + e.w * ak[24];
                s.y += e.x * ak[1] + e.y * ak[9]  + e.z * ak[17] + e.w * ak[25];
                s.z += e.x * ak[2] + e.y * ak[10] + e.z * ak[18] + e.w * ak[26];
                s.w += e.x * ak[3] + e.y * ak[11] + e.z * ak[19] + e.w * ak[27];
            }
            bool feas = mask_feasible(mask, flag, mbase + n0 + n);
            float4 p = make_float4(0.f, 0.f, 0.f, 0.f);
            if (feas) {
                p.x = __expf(s.x); p.y = __expf(s.y);
                p.z = __expf(s.z); p.w = __expf(s.w);
            }
            *(float4*)&cbuf[n][hq] = p;
        }
        __syncthreads();
        // ---- z mini-reduce (wave 0; other waves proceed to accumulate) ----
        if (t < 64) {
            int h = t & 7, seg = t >> 3;
            float z = 0.f;
            for (int nn = seg; nn < TILE; nn += 8) z += cbuf[nn][h];
            z += __shfl_xor(z, 8);
            z += __shfl_xor(z, 16);
            z += __shfl_xor(z, 32);
            if (t < 8) zrun += z;
        }
        // ---- accumulate wemb from LDS tile (p broadcast from cbuf) ----
        for (int nn = jr; nn < TILE; nn += 8) {
            float4 e = tile4[nn][c4 ^ (nn & 31)];
            float4 pA = *(const float4*)&cbuf[nn][0];
            float4 pB = *(const float4*)&cbuf[nn][4];
            wacc[0].x += pA.x * e.x; wacc[0].y += pA.x * e.y; wacc[0].z += pA.x * e.z; wacc[0].w += pA.x * e.w;
            wacc[1].x += pA.y * e.x; wacc[1].y += pA.y * e.y; wacc[1].z += pA.y * e.z; wacc[1].w += pA.y * e.w;
            wacc[2].x += pA.z * e.x; wacc[2].y += pA.z * e.y; wacc[2].z += pA.z * e.z; wacc[2].w += pA.z * e.w;
            wacc[3].x += pA.w * e.x; wacc[3].y += pA.w * e.y; wacc[3].z += pA.w * e.z; wacc[3].w += pA.w * e.w;
            wacc[4].x += pB.x * e.x; wacc[4].y += pB.x * e.y; wacc[4].z += pB.x * e.z; wacc[4].w += pB.x * e.w;
            wacc[5].x += pB.y * e.x; wacc[5].y += pB.y * e.y; wacc[5].z += pB.y * e.z; wacc[5].w += pB.y * e.w;
            wacc[6].x += pB.z * e.x; wacc[6].y += pB.z * e.y; wacc[6].z += pB.z * e.z; wacc[6].w += pB.z * e.w;
            wacc[7].x += pB.w * e.x; wacc[7].y += pB.w * e.y; wacc[7].z += pB.w * e.z; wacc[7].w += pB.w * e.w;
        }
        __syncthreads();   // tile4/cbuf dead before next stage
    }
    if (t < 8) zl[t] = zrun;
    // ---- j-reduce wemb partials (tile4 as [8][32][8] f4 scratch), normalize ----
    {
        float4* red = (float4*)&tile4[0][0];
#pragma unroll
        for (int h = 0; h < HH; ++h) red[(jr * 32 + c4) * 8 + h] = wacc[h];
        __syncthreads();
        int cc = t >> 3, hh = t & 7;
        float4 s = make_float4(0.f, 0.f, 0.f, 0.f);
#pragma unroll
        for (int jj = 0; jj < 8; ++jj) {
            float4 v = red[(jj * 32 + cc) * 8 + hh];
            s.x += v.x; s.y += v.y; s.z += v.z; s.w += v.w;
        }
        float inv = 1.0f / zl[hh];
        s.x *= inv; s.y *= inv; s.z *= inv; s.w *= inv;
        *(float4*)&wemb_s[hh][cc * 4] = s;
    }
    __syncthreads();
    // ---- glimpse tail ----
    if (t < 128) {
        int h = t >> 4;
        float a = 0.f;
        for (int c = 0; c < DD; ++c) a += wemb_s[h][c] * W_node[(size_t)c * 384 + 128 + t];
        small[t] = a;                          // hl
    }
    __syncthreads();
    if (t < 128) {
        float g = 0.f;
        for (int k = 0; k < DD; ++k) g += small[k] * W_out[k * DD + t];
        small[128 + t] = g;                    // gl
    }
    __syncthreads();
    if (t < 128) {
        float a3 = 0.f;
        const float* wr = W_node + (size_t)t * 384 + 256;   // Wl row t
        for (int d = 0; d < DD; ++d) a3 += wr[d] * small[128 + d];
        small[256 + t] = a3;                   // g2
    }
    __syncthreads();
    // ---- logits tail: coalesced half-wave-per-row (R9-validated pattern) ----
    {
        const float4* g2v = (const float4*)&small[256];
        int halfw = t >> 5;                  // 0..7: row within group of 8
        float4 gv = g2v[c4];
        for (int r0 = 0; r0 < NN; r0 += 8) { // 1000 = 125 x 8 exact
            int r = r0 + halfw;
            float4 e = embB4[(size_t)r * 32 + c4];
            float s = e.x * gv.x + e.y * gv.y + e.z * gv.z + e.w * gv.w;
            s += __shfl_xor(s, 1, 32);
            s += __shfl_xor(s, 2, 32);
            s += __shfl_xor(s, 4, 32);
            s += __shfl_xor(s, 8, 32);
            s += __shfl_xor(s, 16, 32);
            if (c4 == 0) {
                bool feas = mask_feasible(mask, flag, mbase + r);
                out[(size_t)mbase + r] = feas ? (10.0f * tanhf(s * 0.08838834764831845f)) : -1.0e30f;
            }
        }
    }
}

extern "C" void kernel_launch(void* const* d_in, const int* in_sizes, int n_in,
                              void* d_out, int out_size, void* d_ws, size_t ws_size,
                              hipStream_t stream) {
    (void)in_sizes; (void)n_in; (void)out_size; (void)ws_size;
    const float* emb     = (const float*)d_in[0];
    const float* ctx     = (const float*)d_in[1];
    const float* W_node  = (const float*)d_in[2];
    const float* W_fixed = (const float*)d_in[3];
    const float* W_step  = (const float*)d_in[4];
    const float* W_out   = (const float*)d_in[5];
    const void*  mask    = d_in[6];
    float* out = (float*)d_out;

    char* ws = (char*)d_ws;
    int*   flag  = (int*)(ws + 0);
    float* Afold = (float*)(ws + WS_AFOLD);

    kA_meanfold<<<BB, 512, 0, stream>>>(emb, ctx, W_fixed, W_step, W_node, Afold,
                                        (const unsigned int*)mask, flag);
    kB_flash<<<BB, 256, 0, stream>>>(emb, Afold, mask, flag, W_node, W_out, out);
}

// Round 23
// 161.249 us; speedup vs baseline: 1.6560x; 1.6560x over previous
//
#include <hip/hip_runtime.h>
#include <math.h>

#define BB 512
#define NN 1000
#define DD 128
#define HH 8
#define TILE 125   // 8 tiles of 125 rows; 4000 float4/tile

// ws layout: flag@0 (4B) | Afold@4096: [B][128][8] f32 (2 MB)
#define WS_AFOLD 4096

__device__ __forceinline__ bool mask_feasible(const void* mask, int flag, int idx) {
    if (flag == 1) return ((const int*)mask)[idx] != 0;
    if (flag == 2) return ((const float*)mask)[idx] != 0.0f;
    return ((const unsigned char*)mask)[idx] != 0;
}

// async 16B global->LDS DMA: per-lane global src addr; LDS dest is
// wave-uniform base + lane*16 (HW). No VGPR round-trip, can't spill.
__device__ __forceinline__ void gload_lds16(const float4* g, float4* l) {
    __builtin_amdgcn_global_load_lds(
        (const __attribute__((address_space(1))) void*)g,
        (__attribute__((address_space(3))) void*)l,
        16, 0, 0);
}

// Fused: mask-dtype detect (block 0, wave 0) + mean over N -> q -> Afold[c][h].
// (validated R4/R12/R19/R22-kA; single-arg launch_bounds only — R5: 2nd arg caused spill.)
__global__ __launch_bounds__(512) void kA_meanfold(
    const float* __restrict__ emb, const float* __restrict__ ctx,
    const float* __restrict__ W_fixed, const float* __restrict__ W_step,
    const float* __restrict__ W_node, float* __restrict__ Afold,
    const unsigned int* __restrict__ maskw, int* __restrict__ flag) {
    int b = blockIdx.x, t = threadIdx.x;
    // ---- k0 fused: detect action_mask storage dtype (block 0, wave 0) ----
    if (b == 0 && t < 64) {
        unsigned int w = maskw[t];
        unsigned long long bi = __ballot(w <= 1u);
        unsigned long long bf = __ballot(w == 0u || w == 0x3F800000u);
        if (t == 0) {
            int f = 0;
            if (bi == ~0ull) f = 1;
            else if (bf == ~0ull) f = 2;
            *flag = f;
        }
    }
    __shared__ float4 red[512];
    __shared__ float mean_s[DD], cld[2 * DD], qlds[DD];
    int q4 = t & 31, j = t >> 5;
    const float4* e4 = (const float4*)(emb + (size_t)b * NN * DD);
    float4 acc = {0.f, 0.f, 0.f, 0.f};
    for (int n = j; n < NN; n += 16) {
        float4 v = e4[n * 32 + q4];
        acc.x += v.x; acc.y += v.y; acc.z += v.z; acc.w += v.w;
    }
    red[t] = acc;
    __syncthreads();
    for (int s = 8; s >= 1; s >>= 1) {
        if (j < s) {
            float4 o = red[t + s * 32], m = red[t];
            m.x += o.x; m.y += o.y; m.z += o.z; m.w += o.w;
            red[t] = m;
        }
        __syncthreads();
    }
    if (t < 32) {
        float4 m = red[t];
        const float inv = 1.0f / (float)NN;
        ((float4*)mean_s)[t] = make_float4(m.x * inv, m.y * inv, m.z * inv, m.w * inv);
    }
    if (t >= 256) cld[t - 256] = ctx[b * 2 * DD + (t - 256)];
    __syncthreads();
    if (t < 128) {
        float a = 0.f;
        for (int c = 0; c < DD; ++c)     a += mean_s[c] * W_fixed[c * DD + t];
        for (int c = 0; c < 2 * DD; ++c) a += cld[c] * W_step[c * DD + t];
        qlds[t] = a;
    }
    __syncthreads();
    if (t < 128) {
        const float* wrow = W_node + (size_t)t * 3 * DD;   // Wk cols [0,128)
        float* A2 = Afold + (size_t)b * 1024;
        for (int h = 0; h < HH; ++h) {
            float a = 0.f;
#pragma unroll
            for (int d0 = 0; d0 < 16; ++d0) a += wrow[h * 16 + d0] * qlds[h * 16 + d0];
            A2[t * 8 + h] = 0.25f * a;   // 1/sqrt(dk) folded
        }
    }
}

// R19's champion kB, byte-identical (DMA staging + SGPR-A compat + no-max
// softmax + per-thread-row logits tail). R22's coalesced tail REVERTED:
// 125 serial dependent-shfl iterations lost to R19's high-ILP row walk.
__global__ __launch_bounds__(256) void kB_flash(
    const float* __restrict__ emb, const float* __restrict__ Afold,
    const void* __restrict__ mask, const int* __restrict__ flagp,
    const float* __restrict__ W_node, const float* __restrict__ W_out,
    float* __restrict__ out) {
    int b = blockIdx.x, t = threadIdx.x;
    int flag = *flagp;
    int wave = t >> 6, lane = t & 63;
    int hq = (t >> 7) * 4;               // waves 0,1 -> h0..3 ; 2,3 -> h4..7
    int n = t & 127;                     // compat row (valid < TILE)
    int c4 = t & 31, jr = t >> 5;        // accumulate role (jr 0..7)

    __shared__ float4 tile4[128][32];    // 64 KB staged tile (XOR-swizzled); reused as j-reduce scratch
    __shared__ float cbuf[128][8];       // 4 KB: p values
    __shared__ float wemb_s[8][128];
    __shared__ float small[3 * DD];      // hl / gl / g2
    __shared__ float zl[HH];

    // wave-uniform scalar base into A: Afold[b][.][hq..hq+3]
    int hqs = __builtin_amdgcn_readfirstlane(hq);
    const float* AbW = Afold + (size_t)b * 1024 + hqs;

    float4 wacc[8];
#pragma unroll
    for (int h = 0; h < HH; ++h) wacc[h] = make_float4(0.f, 0.f, 0.f, 0.f);
    float zrun = 0.f;                    // meaningful on t<8 only

    const float4* embB4 = (const float4*)(emb + (size_t)b * NN * DD);
    const int mbase = b * NN;
    float4* tl = (float4*)tile4;

    for (int tile = 0; tile < 8; ++tile) {
        int n0 = tile * TILE;
        // ---- stage tile -> LDS via async DMA (wave-uniform LDS base,
        //      per-lane pre-swizzled global source; layout == R12) ----
        for (int i = wave; i < 63; i += 4) {
            int p0 = i * 64;                     // wave-uniform linear base
            int p = p0 + lane;
            int r = p >> 5; if (r > 124) r = 124;   // clamp tail overread
            int c = (p & 31) ^ (r & 31);
            gload_lds16(embB4 + (size_t)(n0 + r) * 32 + c, &tl[p0]);
        }
        __syncthreads();                         // drains vmcnt before reads
        // ---- compat from LDS -> p = exp(compat); A from SGPRs ----
        if (n < TILE) {
            int sw = n & 31;
            float4 s = make_float4(0.f, 0.f, 0.f, 0.f);
#pragma unroll 8
            for (int k = 0; k < 32; ++k) {          // col quad c = 4k..4k+3
                float4 e = tile4[n][k ^ sw];
                const float* ak = AbW + k * 32;     // A[4k+j][hq+i] = ak[j*8+i]
                s.x += e.x * ak[0] + e.y * ak[8]  + e.z * ak[16] + e.w * ak[24];
                s.y += e.x * ak[1] + e.y * ak[9]  + e.z * ak[17] + e.w * ak[25];
                s.z += e.x * ak[2] + e.y * ak[10] + e.z * ak[18] + e.w * ak[26];
                s.w += e.x * ak[3] + e.y * ak[11] + e.z * ak[19] + e.w * ak[27];
            }
            bool feas = mask_feasible(mask, flag, mbase + n0 + n);
            float4 p = make_float4(0.f, 0.f, 0.f, 0.f);
            if (feas) {
                p.x = __expf(s.x); p.y = __expf(s.y);
                p.z = __expf(s.z); p.w = __expf(s.w);
            }
            *(float4*)&cbuf[n][hq] = p;
        }
        __syncthreads();
        // ---- z mini-reduce (wave 0; other waves proceed to accumulate) ----
        if (t < 64) {
            int h = t & 7, seg = t >> 3;
            float z = 0.f;
            for (int nn = seg; nn < TILE; nn += 8) z += cbuf[nn][h];
            z += __shfl_xor(z, 8);
            z += __shfl_xor(z, 16);
            z += __shfl_xor(z, 32);
            if (t < 8) zrun += z;
        }
        // ---- accumulate wemb from LDS tile (p broadcast from cbuf) ----
        for (int nn = jr; nn < TILE; nn += 8) {
            float4 e = tile4[nn][c4 ^ (nn & 31)];
            float4 pA = *(const float4*)&cbuf[nn][0];
            float4 pB = *(const float4*)&cbuf[nn][4];
            wacc[0].x += pA.x * e.x; wacc[0].y += pA.x * e.y; wacc[0].z += pA.x * e.z; wacc[0].w += pA.x * e.w;
            wacc[1].x += pA.y * e.x; wacc[1].y += pA.y * e.y; wacc[1].z += pA.y * e.z; wacc[1].w += pA.y * e.w;
            wacc[2].x += pA.z * e.x; wacc[2].y += pA.z * e.y; wacc[2].z += pA.z * e.z; wacc[2].w += pA.z * e.w;
            wacc[3].x += pA.w * e.x; wacc[3].y += pA.w * e.y; wacc[3].z += pA.w * e.z; wacc[3].w += pA.w * e.w;
            wacc[4].x += pB.x * e.x; wacc[4].y += pB.x * e.y; wacc[4].z += pB.x * e.z; wacc[4].w += pB.x * e.w;
            wacc[5].x += pB.y * e.x; wacc[5].y += pB.y * e.y; wacc[5].z += pB.y * e.z; wacc[5].w += pB.y * e.w;
            wacc[6].x += pB.z * e.x; wacc[6].y += pB.z * e.y; wacc[6].z += pB.z * e.z; wacc[6].w += pB.z * e.w;
            wacc[7].x += pB.w * e.x; wacc[7].y += pB.w * e.y; wacc[7].z += pB.w * e.z; wacc[7].w += pB.w * e.w;
        }
        __syncthreads();   // tile4/cbuf dead before next stage
    }
    if (t < 8) zl[t] = zrun;
    // ---- j-reduce wemb partials (tile4 as [8][32][8] f4 scratch), normalize ----
    {
        float4* red = (float4*)&tile4[0][0];
#pragma unroll
        for (int h = 0; h < HH; ++h) red[(jr * 32 + c4) * 8 + h] = wacc[h];
        __syncthreads();
        int cc = t >> 3, hh = t & 7;
        float4 s = make_float4(0.f, 0.f, 0.f, 0.f);
#pragma unroll
        for (int jj = 0; jj < 8; ++jj) {
            float4 v = red[(jj * 32 + cc) * 8 + hh];
            s.x += v.x; s.y += v.y; s.z += v.z; s.w += v.w;
        }
        float inv = 1.0f / zl[hh];
        s.x *= inv; s.y *= inv; s.z *= inv; s.w *= inv;
        *(float4*)&wemb_s[hh][cc * 4] = s;
    }
    __syncthreads();
    // ---- glimpse tail ----
    if (t < 128) {
        int h = t >> 4;
        float a = 0.f;
        for (int c = 0; c < DD; ++c) a += wemb_s[h][c] * W_node[(size_t)c * 384 + 128 + t];
        small[t] = a;                          // hl
    }
    __syncthreads();
    if (t < 128) {
        float g = 0.f;
        for (int k = 0; k < DD; ++k) g += small[k] * W_out[k * DD + t];
        small[128 + t] = g;                    // gl
    }
    __syncthreads();
    if (t < 128) {
        float a3 = 0.f;
        const float* wr = W_node + (size_t)t * 384 + 256;   // Wl row t
        for (int d = 0; d < DD; ++d) a3 += wr[d] * small[128 + d];
        small[256 + t] = a3;                   // g2
    }
    __syncthreads();
    // ---- logits tail (R19's per-thread row walk: high ILP, L2-resident) ----
    const float4* g2v = (const float4*)&small[256];
    for (int r = t; r < NN; r += 256) {
        const float4* row = embB4 + (size_t)r * 32;
        float acc = 0.f;
#pragma unroll 8
        for (int k = 0; k < 32; ++k) {
            float4 e = row[k], g = g2v[k];
            acc += e.x * g.x + e.y * g.y + e.z * g.z + e.w * g.w;
        }
        bool feas = mask_feasible(mask, flag, mbase + r);
        out[(size_t)mbase + r] = feas ? (10.0f * tanhf(acc * 0.08838834764831845f)) : -1.0e30f;
    }
}

extern "C" void kernel_launch(void* const* d_in, const int* in_sizes, int n_in,
                              void* d_out, int out_size, void* d_ws, size_t ws_size,
                              hipStream_t stream) {
    (void)in_sizes; (void)n_in; (void)out_size; (void)ws_size;
    const float* emb     = (const float*)d_in[0];
    const float* ctx     = (const float*)d_in[1];
    const float* W_node  = (const float*)d_in[2];
    const float* W_fixed = (const float*)d_in[3];
    const float* W_step  = (const float*)d_in[4];
    const float* W_out   = (const float*)d_in[5];
    const void*  mask    = d_in[6];
    float* out = (float*)d_out;

    char* ws = (char*)d_ws;
    int*   flag  = (int*)(ws + 0);
    float* Afold = (float*)(ws + WS_AFOLD);

    kA_meanfold<<<BB, 512, 0, stream>>>(emb, ctx, W_fixed, W_step, W_node, Afold,
                                        (const unsigned int*)mask, flag);
    kB_flash<<<BB, 256, 0, stream>>>(emb, Afold, mask, flag, W_node, W_out, out);
}